// Round 13
// baseline (191.607 us; speedup 1.0000x reference)
//
#include <hip/hip_runtime.h>
#include <hip/hip_bf16.h>
#include <float.h>

// N=1024, M=1024, D=512, fp32 in/out.
// tanh(q+k) = 1 - 2/(1+exp2(CS*(q+k))), CS=2*log2(e), exp2 factorized:
// eq[n][d]=min(exp2(CS*qp),2^13), ekT[d][m]=min(exp2(CS*kp),2^13)^T.
// s[n,m] = -2*sum_d Ww[d]/(1+eq*ek) (row-const dropped; softmax shift-inv;
// no max pass). Quad-rational: 4 d-terms share one rcp (rcp 1/8-rate).
// R13: combine kernel + Ph/Pl DELETED. ctx reads S(+mask) directly, builds
// P=mask?exp2(S):0 on the fly (bf16 h/l in-register), computes each row's
// softmax denom locally (full-m block; shuffle reduce), normalizes in
// epilogue. Score: eq/Ww staged ONCE (not per chunk). 3 kernels.
// ws: eq 2MB | ekT 2MB | vph/vpl 2MB | S 4MB = 10.5 MB.

#define NROWS 1024
#define DDIM  512
#define MDIM  1024

typedef __attribute__((ext_vector_type(8))) short s8v;    // 8 bf16, 4 VGPR
typedef __attribute__((ext_vector_type(4))) float f4v;
typedef __attribute__((ext_vector_type(2))) float v2f;

__device__ __forceinline__ ushort f2bf(float f) {
    unsigned u = __float_as_uint(f);
    u = u + 0x7FFFu + ((u >> 16) & 1u);          // RNE
    return (ushort)(u >> 16);
}
__device__ __forceinline__ float bf2f(ushort h) {
    return __uint_as_float(((unsigned)h) << 16);
}

__device__ __forceinline__ void load_lds16(const float* g, float* l) {
    __builtin_amdgcn_global_load_lds(
        (const __attribute__((address_space(1))) void*)g,
        (__attribute__((address_space(3))) void*)l, 16, 0, 0);
}

// ---------------- K1: fused projection GEMMs (MFMA bf16 hi/lo, A^T-B) --------
// z=0: eq[n][d]:  A=q,  B=Wq, bias col, exp2+clamp. Also zeroes S.
// z=1: ekT[d][m]: A=Wk, B=kk, bias row, exp2+clamp.
// z=2: vpT[d][m]: A=Wv, B=v,  bias row, bf16 h/l out.
__global__ __launch_bounds__(256) void proj_gemm(
    const float* __restrict__ q, const float* __restrict__ kk_,
    const float* __restrict__ v,
    const float* __restrict__ Wq, const float* __restrict__ bq,
    const float* __restrict__ Wk, const float* __restrict__ bk,
    const float* __restrict__ Wv, const float* __restrict__ bv,
    float* __restrict__ eq, float* __restrict__ ekT,
    ushort* __restrict__ vph, ushort* __restrict__ vpl,
    float* __restrict__ S, float CS)
{
    __shared__ ushort Ah[4096], Al[4096], Bh[4096], Bl[4096];   // 32 KB

    const float* A; const float* B; const float* bias;
    int biasRow;
    if (blockIdx.z == 0)      { A = q;   B = Wq;  bias = bq; biasRow = 0; }
    else if (blockIdx.z == 1) { A = Wk;  B = kk_; bias = bk; biasRow = 1; }
    else                      { A = Wv;  B = v;   bias = bv; biasRow = 1; }

    const int bi = (blockIdx.z == 0) ? blockIdx.x : blockIdx.y;
    const int bj = (blockIdx.z == 0) ? blockIdx.y : blockIdx.x;

    const int t    = threadIdx.x;
    const int lane = t & 63;
    const int w    = t >> 6;
    const int lm   = lane & 15;
    const int lq   = lane >> 4;
    const int i0   = bi * 64;
    const int j0   = bj * 64;
    const int mh   = (w >> 1) * 32;
    const int nh   = (w & 1) * 32;

    // z==0 has 128 blocks; each zeroes 32KB of S (4MB) for score's atomics
    if (blockIdx.z == 0) {
        const int jb = blockIdx.x * 8 + blockIdx.y;    // 0..127
        float4 zz = {0.f, 0.f, 0.f, 0.f};
#pragma unroll
        for (int p = 0; p < 8; ++p)
            *(float4*)&S[(size_t)jb * 8192 + (t + p * 256) * 4] = zz;
    }

    f4v acc[2][2] = {{{0.f,0.f,0.f,0.f},{0.f,0.f,0.f,0.f}},
                     {{0.f,0.f,0.f,0.f},{0.f,0.f,0.f,0.f}}};
    float4 pa[4], pb[4];

    const int sr = t >> 4, sc4 = t & 15;
#pragma unroll
    for (int p = 0; p < 4; ++p) {
        int r = sr + p * 16;
        pa[p] = *(const float4*)&A[(size_t)(i0 + r) * DDIM + sc4 * 4];
        pb[p] = *(const float4*)&B[(size_t)(j0 + r) * DDIM + sc4 * 4];
    }

    for (int kc = 0; kc < 8; ++kc) {
        __syncthreads();
#pragma unroll
        for (int p = 0; p < 4; ++p) {
            int r = sr + p * 16;
            int ad = r * 64 + (((sc4 >> 1) ^ (r & 7)) << 3) + (sc4 & 1) * 4;
            float af[4] = {pa[p].x, pa[p].y, pa[p].z, pa[p].w};
            float bf[4] = {pb[p].x, pb[p].y, pb[p].z, pb[p].w};
            ushort ah4[4], al4[4], bh4[4], bl4[4];
#pragma unroll
            for (int e = 0; e < 4; ++e) {
                ah4[e] = f2bf(af[e]); al4[e] = f2bf(af[e] - bf2f(ah4[e]));
                bh4[e] = f2bf(bf[e]); bl4[e] = f2bf(bf[e] - bf2f(bh4[e]));
            }
            *(ushort4*)&Ah[ad] = *(ushort4*)ah4;
            *(ushort4*)&Al[ad] = *(ushort4*)al4;
            *(ushort4*)&Bh[ad] = *(ushort4*)bh4;
            *(ushort4*)&Bl[ad] = *(ushort4*)bl4;
        }
        __syncthreads();
        if (kc < 7) {
            const int k0 = (kc + 1) * 64;
#pragma unroll
            for (int p = 0; p < 4; ++p) {
                int r = sr + p * 16;
                pa[p] = *(const float4*)&A[(size_t)(i0 + r) * DDIM + k0 + sc4 * 4];
                pb[p] = *(const float4*)&B[(size_t)(j0 + r) * DDIM + k0 + sc4 * 4];
            }
        }
#pragma unroll
        for (int ks = 0; ks < 2; ++ks) {
            const int kb = ks * 4 + lq;
            s8v afh[2], afl[2], bfh[2], bfl[2];
#pragma unroll
            for (int g = 0; g < 2; ++g) {
                int ra = mh + g * 16 + lm;
                int rb = nh + g * 16 + lm;
                int aa = ra * 64 + ((kb ^ (ra & 7)) << 3);
                int ab = rb * 64 + ((kb ^ (rb & 7)) << 3);
                afh[g] = *(const s8v*)&Ah[aa];
                afl[g] = *(const s8v*)&Al[aa];
                bfh[g] = *(const s8v*)&Bh[ab];
                bfl[g] = *(const s8v*)&Bl[ab];
            }
#pragma unroll
            for (int mi = 0; mi < 2; ++mi)
#pragma unroll
                for (int ni = 0; ni < 2; ++ni) {
                    acc[mi][ni] = __builtin_amdgcn_mfma_f32_16x16x32_bf16(
                        afh[mi], bfh[ni], acc[mi][ni], 0, 0, 0);
                    acc[mi][ni] = __builtin_amdgcn_mfma_f32_16x16x32_bf16(
                        afh[mi], bfl[ni], acc[mi][ni], 0, 0, 0);
                    acc[mi][ni] = __builtin_amdgcn_mfma_f32_16x16x32_bf16(
                        afl[mi], bfh[ni], acc[mi][ni], 0, 0, 0);
                }
        }
    }

    const float CLAMP = 8192.0f;   // 2^13: quad-rational den < 2^127
#pragma unroll
    for (int mi = 0; mi < 2; ++mi) {
#pragma unroll
        for (int ni = 0; ni < 2; ++ni) {
#pragma unroll
            for (int p = 0; p < 4; ++p) {
                int row = i0 + mh + mi * 16 + lq * 4 + p;
                int col = j0 + nh + ni * 16 + lm;
                float val = acc[mi][ni][p] + (biasRow ? bias[row] : bias[col]);
                if (blockIdx.z == 0) {
                    eq[(size_t)row * 512 + col] =
                        fminf(__builtin_amdgcn_exp2f(val * CS), CLAMP);
                } else if (blockIdx.z == 1) {
                    ekT[(size_t)row * 1024 + col] =
                        fminf(__builtin_amdgcn_exp2f(val * CS), CLAMP);
                } else {
                    ushort h = f2bf(val);
                    vph[(size_t)row * 1024 + col] = h;
                    vpl[(size_t)row * 1024 + col] = f2bf(val - bf2f(h));
                }
            }
        }
    }
}

// ---------------- K2: score (d-split x2, atomic S accumulation) --------------
// S[n][m] += C2 * sum_{d in half} Ww[d]/(1+eq[n][d]*ekT[d][m])
// 4 waves; wave w owns 4 n; lane owns 2 m. Block 16n x 128m x 256d.
// eq (16x256) + Ww (256) staged ONCE; per-chunk only ks via global_load_lds.
#define DCH  32
#define SMCH 128
__global__ __launch_bounds__(256) void score_kernel(const float* __restrict__ eq,
                                                    const float* __restrict__ ekT,
                                                    const float* __restrict__ Ww,
                                                    float* __restrict__ S)
{
    __shared__ __align__(16) float ks[DCH * SMCH];   // 16 KB
    __shared__ __align__(16) float es[16 * 256];     // 16 KB (whole d-half)
    __shared__ __align__(16) float wws[256];         // 1 KB
    const int t    = threadIdx.x;
    const int lane = t & 63;
    const int w    = t >> 6;
    const int m0   = blockIdx.x * SMCH;
    const int n0   = blockIdx.y * 16;
    const int dbase = blockIdx.z * 256;

    // stage eq rows + Ww once (coalesced float4)
#pragma unroll
    for (int p = 0; p < 4; ++p) {
        int idx = t + p * 256;                       // 1024 float4-slots
        int nl = idx >> 6, dd4 = idx & 63;
        *(float4*)&es[nl * 256 + dd4 * 4] =
            *(const float4*)&eq[(size_t)(n0 + nl) * DDIM + dbase + dd4 * 4];
    }
    wws[t] = Ww[dbase + t];

    v2f acc[4] = {};
    const v2f one2 = {1.f, 1.f};

    for (int dc = 0; dc < 256; dc += DCH) {
        const int d0 = dbase + dc;
        __syncthreads();
#pragma unroll
        for (int i = 0; i < 4; ++i) {
            int r2 = w * 8 + i * 2;                              // wave-uniform
            const float* g = ekT + (size_t)(d0 + r2 + (lane >> 5)) * MDIM
                             + m0 + (lane & 31) * 4;
            load_lds16(g, &ks[r2 * SMCH]);
        }
        __syncthreads();   // drains vmcnt -> ks visible (es/wws after 1st)

#pragma unroll
        for (int dq = 0; dq < DCH; dq += 4) {
            v2f k0 = *(const v2f*)&ks[(dq + 0) * SMCH + lane * 2];
            v2f k1 = *(const v2f*)&ks[(dq + 1) * SMCH + lane * 2];
            v2f k2 = *(const v2f*)&ks[(dq + 2) * SMCH + lane * 2];
            v2f k3 = *(const v2f*)&ks[(dq + 3) * SMCH + lane * 2];
            float4 wg = *(const float4*)&wws[dc + dq];
#pragma unroll
            for (int nn = 0; nn < 4; ++nn) {
                float4 eg = *(const float4*)&es[(w * 4 + nn) * 256 + dc + dq];
                v2f A0 = __builtin_elementwise_fma(k0, (v2f){eg.x, eg.x}, one2);
                v2f A1 = __builtin_elementwise_fma(k1, (v2f){eg.y, eg.y}, one2);
                v2f A2 = __builtin_elementwise_fma(k2, (v2f){eg.z, eg.z}, one2);
                v2f A3 = __builtin_elementwise_fma(k3, (v2f){eg.w, eg.w}, one2);
                v2f n01 = __builtin_elementwise_fma((v2f){wg.y, wg.y}, A0,
                                                    (v2f){wg.x, wg.x} * A1);
                v2f d01 = A0 * A1;
                v2f n23 = __builtin_elementwise_fma((v2f){wg.w, wg.w}, A2,
                                                    (v2f){wg.z, wg.z} * A3);
                v2f d23 = A2 * A3;
                v2f num = __builtin_elementwise_fma(n01, d23, n23 * d01);
                v2f den = d01 * d23;
                v2f r = {__builtin_amdgcn_rcpf(den.x), __builtin_amdgcn_rcpf(den.y)};
                acc[nn] = __builtin_elementwise_fma(num, r, acc[nn]);
            }
        }
    }

    const float C2 = -2.8853900817779268f;   // -2*log2(e)
    const int m = m0 + lane * 2;
#pragma unroll
    for (int nn = 0; nn < 4; ++nn) {
        int n = n0 + w * 4 + nn;
        atomicAdd(&S[(size_t)n * MDIM + m],     acc[nn].x * C2);
        atomicAdd(&S[(size_t)n * MDIM + m + 1], acc[nn].y * C2);
    }
}

// ---------------- K3: context MFMA + fused softmax-normalize -----------------
// P[n][m] = mask ? exp2(S[n][m]) : 0 built on the fly (bf16 h/l, in-register);
// out[n][d] = (sum_m P*vpT[d][m]) / (sum_m P). Block spans full m -> each
// wave computes its rows' denominators locally (shuffle reduce, no atomics).
// Wave = one 16x16 D-tile. Grid (8 d-groups, 64 n-tiles) = 512 blocks.
__global__ __launch_bounds__(256) void ctx_gemm(const float* __restrict__ S,
                                                const int* __restrict__ mask,
                                                const ushort* __restrict__ vph,
                                                const ushort* __restrict__ vpl,
                                                float* __restrict__ out)
{
    const int t    = threadIdx.x;
    const int lane = t & 63;
    const int w    = t >> 6;
    const int lm   = lane & 15;
    const int lq   = lane >> 4;
    const int d0   = blockIdx.x * 64 + w * 16;
    const int n0   = blockIdx.y * 16;

    const float*  pS = S    + (size_t)(n0 + lm) * MDIM + lq * 8;
    const int*    pM = mask + (size_t)(n0 + lm) * MDIM + lq * 8;
    const ushort* pBh = vph + (size_t)(d0 + lm) * MDIM + lq * 8;
    const ushort* pBl = vpl + (size_t)(d0 + lm) * MDIM + lq * 8;

    f4v acc = {0.f, 0.f, 0.f, 0.f};
    float rs = 0.f;
#pragma unroll 4
    for (int m0 = 0; m0 < MDIM; m0 += 32) {
        float4 sA = *(const float4*)(pS + m0);
        float4 sB = *(const float4*)(pS + m0 + 4);
        int4   mA = *(const int4*)(pM + m0);
        int4   mB = *(const int4*)(pM + m0 + 4);
        float pv[8];
        pv[0] = mA.x ? __builtin_amdgcn_exp2f(sA.x) : 0.f;
        pv[1] = mA.y ? __builtin_amdgcn_exp2f(sA.y) : 0.f;
        pv[2] = mA.z ? __builtin_amdgcn_exp2f(sA.z) : 0.f;
        pv[3] = mA.w ? __builtin_amdgcn_exp2f(sA.w) : 0.f;
        pv[4] = mB.x ? __builtin_amdgcn_exp2f(sB.x) : 0.f;
        pv[5] = mB.y ? __builtin_amdgcn_exp2f(sB.y) : 0.f;
        pv[6] = mB.z ? __builtin_amdgcn_exp2f(sB.z) : 0.f;
        pv[7] = mB.w ? __builtin_amdgcn_exp2f(sB.w) : 0.f;
        ushort hh[8], ll[8];
#pragma unroll
        for (int j = 0; j < 8; ++j) {
            hh[j] = f2bf(pv[j]);
            ll[j] = f2bf(pv[j] - bf2f(hh[j]));
            rs += pv[j];
        }
        s8v ah = *(const s8v*)hh;
        s8v al = *(const s8v*)ll;
        s8v bh = *(const s8v*)(pBh + m0);
        s8v bl = *(const s8v*)(pBl + m0);
        acc = __builtin_amdgcn_mfma_f32_16x16x32_bf16(ah, bh, acc, 0, 0, 0);
        acc = __builtin_amdgcn_mfma_f32_16x16x32_bf16(ah, bl, acc, 0, 0, 0);
        acc = __builtin_amdgcn_mfma_f32_16x16x32_bf16(al, bh, acc, 0, 0, 0);
    }

    // rs currently: partial row-sum of row n0+lm over this lane's m-slice.
    // Combine the 4 quads (lanes sharing lm) -> full row sums everywhere.
    rs += __shfl_xor(rs, 16);
    rs += __shfl_xor(rs, 32);

#pragma unroll
    for (int p = 0; p < 4; ++p) {
        int nrow = n0 + lq * 4 + p;
        float rtot = __shfl(rs, lq * 4 + p);       // row-sum of nrow (from lane lm=lq*4+p)
        float inv = __builtin_amdgcn_rcpf(rtot);
        out[(size_t)nrow * DDIM + d0 + lm] = acc[p] * inv;
    }
}

extern "C" void kernel_launch(void* const* d_in, const int* in_sizes, int n_in,
                              void* d_out, int out_size, void* d_ws, size_t ws_size,
                              hipStream_t stream)
{
    const float* q    = (const float*)d_in[0];
    const float* k    = (const float*)d_in[1];
    const float* v    = (const float*)d_in[2];
    const int*   mask = (const int*)d_in[3];
    const float* Wq   = (const float*)d_in[4];
    const float* bq   = (const float*)d_in[5];
    const float* Wk   = (const float*)d_in[6];
    const float* bk   = (const float*)d_in[7];
    const float* Wv   = (const float*)d_in[8];
    const float* bv   = (const float*)d_in[9];
    const float* Ww   = (const float*)d_in[10];
    // d_in[11] (bw) cancels under softmax.

    float* ws    = (float*)d_ws;
    float* eq    = ws;                       // 512K floats [1024 n][512 d]
    float* ekT   = ws + 524288;              // 512K [512 d][1024 m]
    ushort* vph  = (ushort*)(ws + 1048576);  // 1M ushorts [512 d][1024 m]
    ushort* vpl  = (ushort*)(ws + 1310720);  // 1M ushorts
    float* S     = ws + 1572864;             // 1M floats [1024 n][1024 m]
    float* out   = (float*)d_out;

    const float CS = 2.8853900817779268f;    // 2*log2(e)

    proj_gemm<<<dim3(16, 8, 3), dim3(256), 0, stream>>>(q, k, v, Wq, bq, Wk, bk,
                                                        Wv, bv, eq, ekT,
                                                        vph, vpl, S, CS);
    score_kernel<<<dim3(8, 64, 2), dim3(256), 0, stream>>>(eq, ekT, Ww, S);
    ctx_gemm<<<dim3(8, 64), dim3(256), 0, stream>>>(S, mask, vph, vpl, out);
}

// Round 14
// 181.367 us; speedup vs baseline: 1.0565x; 1.0565x over previous
//
#include <hip/hip_runtime.h>
#include <hip/hip_bf16.h>
#include <float.h>

// N=1024, M=1024, D=512, fp32 in/out.
// tanh(q+k) = 1 - 2/(1+exp2(CS*(q+k))), CS=2*log2(e), exp2 factorized:
// eq[n][d]=min(exp2(CS*qp),2^13), ekT[d][m]=min(exp2(CS*kp),2^13)^T.
// s[n,m] = -2*sum_d Ww[d]/(1+eq*ek) (row-const dropped; softmax shift-inv;
// no max pass). Quad-rational: 4 d-terms share one rcp (rcp 1/8-rate).
// R14 = R12 structure (proj, score, combine, ctx) + occupancy/straggler
// fixes: proj 64x32 tiles -> 768 blocks (exactly 3/CU, no straggler round);
// ctx m-split x2 -> 1024 blocks (4/CU), normalized atomicAdd into out
// (pre-zeroed by proj z2 blocks). Score/combine = R12/R13 measured-stable.
// ws: eq 2MB | ekT 2MB | vph/vpl 2MB | S 4MB = 10.5MB. Ph/Pl overlay eq/ekT.

#define NROWS 1024
#define DDIM  512
#define MDIM  1024

typedef __attribute__((ext_vector_type(8))) short s8v;    // 8 bf16, 4 VGPR
typedef __attribute__((ext_vector_type(4))) float f4v;
typedef __attribute__((ext_vector_type(2))) float v2f;

__device__ __forceinline__ ushort f2bf(float f) {
    unsigned u = __float_as_uint(f);
    u = u + 0x7FFFu + ((u >> 16) & 1u);          // RNE
    return (ushort)(u >> 16);
}
__device__ __forceinline__ float bf2f(ushort h) {
    return __uint_as_float(((unsigned)h) << 16);
}

__device__ __forceinline__ void load_lds16(const float* g, float* l) {
    __builtin_amdgcn_global_load_lds(
        (const __attribute__((address_space(1))) void*)g,
        (__attribute__((address_space(3))) void*)l, 16, 0, 0);
}

// ---------------- K1: fused projection GEMMs (MFMA bf16 hi/lo, A^T-B) --------
// out[R][C] = sum_k A[r][k]*B[c][k] (+bias, epilogue per z). 64(R)x32(C)
// tile -> 256 tiles per z, grid (16,16,3) = 768 blocks = 3/CU exactly.
// z=0: eq[n][d]:  A=q(1024xK),  B=Wq(512xK), bias col, exp2+clamp. Zeroes S.
// z=1: ekT[d][m]: A=Wk(512xK),  B=k(1024xK), bias row, exp2+clamp.
// z=2: vpT[d][m]: A=Wv(512xK),  B=v(1024xK), bias row, bf16 h/l. Zeroes out.
__global__ __launch_bounds__(256) void proj_gemm(
    const float* __restrict__ q, const float* __restrict__ kk_,
    const float* __restrict__ v,
    const float* __restrict__ Wq, const float* __restrict__ bq,
    const float* __restrict__ Wk, const float* __restrict__ bk,
    const float* __restrict__ Wv, const float* __restrict__ bv,
    float* __restrict__ eq, float* __restrict__ ekT,
    ushort* __restrict__ vph, ushort* __restrict__ vpl,
    float* __restrict__ S, float* __restrict__ outz, float CS)
{
    __shared__ ushort Ah[4096], Al[4096];   // 64 r x 64 k
    __shared__ ushort Bh[2048], Bl[2048];   // 32 c x 64 k   (24 KB total)

    const float* A; const float* B; const float* bias;
    int biasRow;
    if (blockIdx.z == 0)      { A = q;   B = Wq;  bias = bq; biasRow = 0; }
    else if (blockIdx.z == 1) { A = Wk;  B = kk_; bias = bk; biasRow = 1; }
    else                      { A = Wv;  B = v;   bias = bv; biasRow = 1; }

    const int t    = threadIdx.x;
    const int flat = blockIdx.y * 16 + blockIdx.x;   // 0..255
    // z0: R=1024 (16 tiles) x C=512 (16); z1,z2: R=512 (8) x C=1024 (32)
    const int bi = (blockIdx.z == 0) ? (flat >> 4) : (flat >> 5);
    const int bj = (blockIdx.z == 0) ? (flat & 15) : (flat & 31);

    const int lane = t & 63;
    const int w    = t >> 6;
    const int lm   = lane & 15;
    const int lq   = lane >> 4;
    const int i0   = bi * 64;
    const int j0   = bj * 32;
    const int mh   = (w >> 1) * 32;       // wave row-half (2x 16-row tiles)
    const int nh   = (w & 1) * 16;        // wave col-group (one 16-col tile)

    // zeroing for later atomics: z0 blocks zero S (16KB each), z2 zero out (8KB)
    if (blockIdx.z == 0) {
        float4 zz = {0.f, 0.f, 0.f, 0.f};
#pragma unroll
        for (int p = 0; p < 4; ++p)
            *(float4*)&S[(size_t)flat * 4096 + (t + p * 256) * 4] = zz;
    } else if (blockIdx.z == 2) {
        float4 zz = {0.f, 0.f, 0.f, 0.f};
#pragma unroll
        for (int p = 0; p < 2; ++p)
            *(float4*)&outz[(size_t)flat * 2048 + (t + p * 256) * 4] = zz;
    }

    f4v acc[2] = {{0.f,0.f,0.f,0.f},{0.f,0.f,0.f,0.f}};
    float4 pa[4], pb[2];

    const int sr = t >> 4, sc4 = t & 15;  // staging row / k-quad
#pragma unroll
    for (int p = 0; p < 4; ++p)
        pa[p] = *(const float4*)&A[(size_t)(i0 + sr + p * 16) * DDIM + sc4 * 4];
#pragma unroll
    for (int p = 0; p < 2; ++p)
        pb[p] = *(const float4*)&B[(size_t)(j0 + sr + p * 16) * DDIM + sc4 * 4];

    for (int kc = 0; kc < 8; ++kc) {
        __syncthreads();
#pragma unroll
        for (int p = 0; p < 4; ++p) {
            int r = sr + p * 16;
            int ad = r * 64 + (((sc4 >> 1) ^ (r & 7)) << 3) + (sc4 & 1) * 4;
            float af[4] = {pa[p].x, pa[p].y, pa[p].z, pa[p].w};
            ushort h4[4], l4[4];
#pragma unroll
            for (int e = 0; e < 4; ++e) {
                h4[e] = f2bf(af[e]); l4[e] = f2bf(af[e] - bf2f(h4[e]));
            }
            *(ushort4*)&Ah[ad] = *(ushort4*)h4;
            *(ushort4*)&Al[ad] = *(ushort4*)l4;
        }
#pragma unroll
        for (int p = 0; p < 2; ++p) {
            int r = sr + p * 16;
            int ad = r * 64 + (((sc4 >> 1) ^ (r & 7)) << 3) + (sc4 & 1) * 4;
            float bf[4] = {pb[p].x, pb[p].y, pb[p].z, pb[p].w};
            ushort h4[4], l4[4];
#pragma unroll
            for (int e = 0; e < 4; ++e) {
                h4[e] = f2bf(bf[e]); l4[e] = f2bf(bf[e] - bf2f(h4[e]));
            }
            *(ushort4*)&Bh[ad] = *(ushort4*)h4;
            *(ushort4*)&Bl[ad] = *(ushort4*)l4;
        }
        __syncthreads();
        if (kc < 7) {
            const int k0 = (kc + 1) * 64;
#pragma unroll
            for (int p = 0; p < 4; ++p)
                pa[p] = *(const float4*)&A[(size_t)(i0 + sr + p * 16) * DDIM + k0 + sc4 * 4];
#pragma unroll
            for (int p = 0; p < 2; ++p)
                pb[p] = *(const float4*)&B[(size_t)(j0 + sr + p * 16) * DDIM + k0 + sc4 * 4];
        }
#pragma unroll
        for (int ks = 0; ks < 2; ++ks) {
            const int kb = ks * 4 + lq;
            s8v afh[2], afl[2];
#pragma unroll
            for (int mi = 0; mi < 2; ++mi) {
                int ra = mh + mi * 16 + lm;
                int aa = ra * 64 + ((kb ^ (ra & 7)) << 3);
                afh[mi] = *(const s8v*)&Ah[aa];
                afl[mi] = *(const s8v*)&Al[aa];
            }
            int rb = nh + lm;
            int ab = rb * 64 + ((kb ^ (rb & 7)) << 3);
            s8v bfh = *(const s8v*)&Bh[ab];
            s8v bfl = *(const s8v*)&Bl[ab];
#pragma unroll
            for (int mi = 0; mi < 2; ++mi) {
                acc[mi] = __builtin_amdgcn_mfma_f32_16x16x32_bf16(afh[mi], bfh, acc[mi], 0, 0, 0);
                acc[mi] = __builtin_amdgcn_mfma_f32_16x16x32_bf16(afh[mi], bfl, acc[mi], 0, 0, 0);
                acc[mi] = __builtin_amdgcn_mfma_f32_16x16x32_bf16(afl[mi], bfh, acc[mi], 0, 0, 0);
            }
        }
    }

    const float CLAMP = 8192.0f;   // 2^13: quad-rational den < 2^127
    const int C = (blockIdx.z == 0) ? 512 : 1024;
#pragma unroll
    for (int mi = 0; mi < 2; ++mi) {
#pragma unroll
        for (int p = 0; p < 4; ++p) {
            int row = i0 + mh + mi * 16 + lq * 4 + p;
            int col = j0 + nh + lm;
            float val = acc[mi][p] + (biasRow ? bias[row] : bias[col]);
            if (blockIdx.z == 0) {
                eq[(size_t)row * 512 + col] =
                    fminf(__builtin_amdgcn_exp2f(val * CS), CLAMP);
            } else if (blockIdx.z == 1) {
                ekT[(size_t)row * 1024 + col] =
                    fminf(__builtin_amdgcn_exp2f(val * CS), CLAMP);
            } else {
                ushort h = f2bf(val);
                vph[(size_t)row * 1024 + col] = h;
                vpl[(size_t)row * 1024 + col] = f2bf(val - bf2f(h));
            }
        }
    }
    (void)C;
}

// ---------------- K2: score (d-split x2, atomic S accumulation) --------------
// S[n][m] += C2 * sum_{d in half} Ww[d]/(1+eq[n][d]*ekT[d][m])
// 4 waves; wave w owns 4 n; lane owns 2 m. Block 16n x 128m x 256d.
// eq (16x256) + Ww staged once; per-chunk only ks via global_load_lds.
#define DCH  32
#define SMCH 128
__global__ __launch_bounds__(256) void score_kernel(const float* __restrict__ eq,
                                                    const float* __restrict__ ekT,
                                                    const float* __restrict__ Ww,
                                                    float* __restrict__ S)
{
    __shared__ __align__(16) float ks[DCH * SMCH];   // 16 KB
    __shared__ __align__(16) float es[16 * 256];     // 16 KB (whole d-half)
    __shared__ __align__(16) float wws[256];         // 1 KB
    const int t    = threadIdx.x;
    const int lane = t & 63;
    const int w    = t >> 6;
    const int m0   = blockIdx.x * SMCH;
    const int n0   = blockIdx.y * 16;
    const int dbase = blockIdx.z * 256;

#pragma unroll
    for (int p = 0; p < 4; ++p) {
        int idx = t + p * 256;
        int nl = idx >> 6, dd4 = idx & 63;
        *(float4*)&es[nl * 256 + dd4 * 4] =
            *(const float4*)&eq[(size_t)(n0 + nl) * DDIM + dbase + dd4 * 4];
    }
    wws[t] = Ww[dbase + t];

    v2f acc[4] = {};
    const v2f one2 = {1.f, 1.f};

    for (int dc = 0; dc < 256; dc += DCH) {
        const int d0 = dbase + dc;
        __syncthreads();
#pragma unroll
        for (int i = 0; i < 4; ++i) {
            int r2 = w * 8 + i * 2;                              // wave-uniform
            const float* g = ekT + (size_t)(d0 + r2 + (lane >> 5)) * MDIM
                             + m0 + (lane & 31) * 4;
            load_lds16(g, &ks[r2 * SMCH]);
        }
        __syncthreads();   // drains vmcnt -> ks visible

#pragma unroll
        for (int dq = 0; dq < DCH; dq += 4) {
            v2f k0 = *(const v2f*)&ks[(dq + 0) * SMCH + lane * 2];
            v2f k1 = *(const v2f*)&ks[(dq + 1) * SMCH + lane * 2];
            v2f k2 = *(const v2f*)&ks[(dq + 2) * SMCH + lane * 2];
            v2f k3 = *(const v2f*)&ks[(dq + 3) * SMCH + lane * 2];
            float4 wg = *(const float4*)&wws[dc + dq];
#pragma unroll
            for (int nn = 0; nn < 4; ++nn) {
                float4 eg = *(const float4*)&es[(w * 4 + nn) * 256 + dc + dq];
                v2f A0 = __builtin_elementwise_fma(k0, (v2f){eg.x, eg.x}, one2);
                v2f A1 = __builtin_elementwise_fma(k1, (v2f){eg.y, eg.y}, one2);
                v2f A2 = __builtin_elementwise_fma(k2, (v2f){eg.z, eg.z}, one2);
                v2f A3 = __builtin_elementwise_fma(k3, (v2f){eg.w, eg.w}, one2);
                v2f n01 = __builtin_elementwise_fma((v2f){wg.y, wg.y}, A0,
                                                    (v2f){wg.x, wg.x} * A1);
                v2f d01 = A0 * A1;
                v2f n23 = __builtin_elementwise_fma((v2f){wg.w, wg.w}, A2,
                                                    (v2f){wg.z, wg.z} * A3);
                v2f d23 = A2 * A3;
                v2f num = __builtin_elementwise_fma(n01, d23, n23 * d01);
                v2f den = d01 * d23;
                v2f r = {__builtin_amdgcn_rcpf(den.x), __builtin_amdgcn_rcpf(den.y)};
                acc[nn] = __builtin_elementwise_fma(num, r, acc[nn]);
            }
        }
    }

    const float C2 = -2.8853900817779268f;   // -2*log2(e)
    const int m = m0 + lane * 2;
#pragma unroll
    for (int nn = 0; nn < 4; ++nn) {
        int n = n0 + w * 4 + nn;
        atomicAdd(&S[(size_t)n * MDIM + m],     acc[nn].x * C2);
        atomicAdd(&S[(size_t)n * MDIM + m + 1], acc[nn].y * C2);
    }
}

// ---------------- K2b: combine S -> P(bf16 h/l) + rowsum ---------------------
__global__ __launch_bounds__(256) void combine_kernel(const float* __restrict__ S,
                                                      const int* __restrict__ mask,
                                                      ushort* __restrict__ Ph,
                                                      ushort* __restrict__ Pl,
                                                      float* __restrict__ rsum)
{
    __shared__ float red[4];
    const int n = blockIdx.x, t = threadIdx.x;
    const int lane = t & 63, w = t >> 6;

    float4 s  = *(const float4*)&S[(size_t)n * MDIM + t * 4];
    int4   mk = *(const int4*)&mask[(size_t)n * MDIM + t * 4];
    float p0 = mk.x ? __builtin_amdgcn_exp2f(s.x) : 0.f;
    float p1 = mk.y ? __builtin_amdgcn_exp2f(s.y) : 0.f;
    float p2 = mk.z ? __builtin_amdgcn_exp2f(s.z) : 0.f;
    float p3 = mk.w ? __builtin_amdgcn_exp2f(s.w) : 0.f;

    ushort h[4] = {f2bf(p0), f2bf(p1), f2bf(p2), f2bf(p3)};
    ushort l[4] = {f2bf(p0 - bf2f(h[0])), f2bf(p1 - bf2f(h[1])),
                   f2bf(p2 - bf2f(h[2])), f2bf(p3 - bf2f(h[3]))};
    *(ushort4*)&Ph[(size_t)n * MDIM + t * 4] = *(ushort4*)h;
    *(ushort4*)&Pl[(size_t)n * MDIM + t * 4] = *(ushort4*)l;

    float rs = (p0 + p1) + (p2 + p3);
#pragma unroll
    for (int off = 32; off; off >>= 1) rs += __shfl_xor(rs, off);
    if (lane == 0) red[w] = rs;
    __syncthreads();
    if (t == 0) rsum[n] = (red[0] + red[1]) + (red[2] + red[3]);
}

// ---------------- K3: context MFMA (LDS-free, m-split x2, atomic out) --------
// out[n][d] += (sum_{m in half} P[n][m]*vpT[d][m]) * rcp(rsum[n])
// Wave = one 16x16 D-tile. Grid (8 d-groups, 64 n-tiles, 2 m-halves) = 1024
// blocks = 4/CU. out pre-zeroed by proj z2.
__global__ __launch_bounds__(256) void ctx_gemm(const ushort* __restrict__ Ph,
                                                const ushort* __restrict__ Pl,
                                                const ushort* __restrict__ vph,
                                                const ushort* __restrict__ vpl,
                                                const float* __restrict__ rsum,
                                                float* __restrict__ out)
{
    const int t    = threadIdx.x;
    const int lane = t & 63;
    const int w    = t >> 6;
    const int lm   = lane & 15;
    const int lq   = lane >> 4;
    const int d0   = blockIdx.x * 64 + w * 16;
    const int n0   = blockIdx.y * 16;
    const int mb   = blockIdx.z * 512;

    const ushort* pAh = Ph  + (size_t)(n0 + lm) * MDIM + mb + lq * 8;
    const ushort* pAl = Pl  + (size_t)(n0 + lm) * MDIM + mb + lq * 8;
    const ushort* pBh = vph + (size_t)(d0 + lm) * MDIM + mb + lq * 8;
    const ushort* pBl = vpl + (size_t)(d0 + lm) * MDIM + mb + lq * 8;

    f4v acc = {0.f, 0.f, 0.f, 0.f};
#pragma unroll 4
    for (int m0 = 0; m0 < 512; m0 += 32) {
        s8v ah = *(const s8v*)(pAh + m0);
        s8v al = *(const s8v*)(pAl + m0);
        s8v bh = *(const s8v*)(pBh + m0);
        s8v bl = *(const s8v*)(pBl + m0);
        acc = __builtin_amdgcn_mfma_f32_16x16x32_bf16(ah, bh, acc, 0, 0, 0);
        acc = __builtin_amdgcn_mfma_f32_16x16x32_bf16(ah, bl, acc, 0, 0, 0);
        acc = __builtin_amdgcn_mfma_f32_16x16x32_bf16(al, bh, acc, 0, 0, 0);
    }

#pragma unroll
    for (int p = 0; p < 4; ++p) {
        int nrow = n0 + lq * 4 + p;
        float inv = __builtin_amdgcn_rcpf(rsum[nrow]);
        atomicAdd(&out[(size_t)nrow * DDIM + d0 + lm], acc[p] * inv);
    }
}

extern "C" void kernel_launch(void* const* d_in, const int* in_sizes, int n_in,
                              void* d_out, int out_size, void* d_ws, size_t ws_size,
                              hipStream_t stream)
{
    const float* q    = (const float*)d_in[0];
    const float* k    = (const float*)d_in[1];
    const float* v    = (const float*)d_in[2];
    const int*   mask = (const int*)d_in[3];
    const float* Wq   = (const float*)d_in[4];
    const float* bq   = (const float*)d_in[5];
    const float* Wk   = (const float*)d_in[6];
    const float* bk   = (const float*)d_in[7];
    const float* Wv   = (const float*)d_in[8];
    const float* bv   = (const float*)d_in[9];
    const float* Ww   = (const float*)d_in[10];
    // d_in[11] (bw) cancels under softmax.

    float* ws    = (float*)d_ws;
    float* eq    = ws;                       // 512K floats [1024 n][512 d]
    float* ekT   = ws + 524288;              // 512K [512 d][1024 m]
    ushort* vph  = (ushort*)(ws + 1048576);  // 1M ushorts [512 d][1024 m]
    ushort* vpl  = (ushort*)(ws + 1310720);  // 1M ushorts
    float* S     = ws + 1572864;             // 1M floats [1024 n][1024 m]
    float* rsum  = ws + 2621440;             // 1K floats
    // Ph/Pl OVERLAY eq/ekT (dead after score; written by combine):
    ushort* Ph   = (ushort*)ws;              // 1M ushorts [1024 n][1024 m]
    ushort* Pl   = (ushort*)(ws + 524288);   // 1M ushorts
    float* out   = (float*)d_out;

    const float CS = 2.8853900817779268f;    // 2*log2(e)

    proj_gemm<<<dim3(16, 16, 3), dim3(256), 0, stream>>>(q, k, v, Wq, bq, Wk, bk,
                                                         Wv, bv, eq, ekT,
                                                         vph, vpl, S, out, CS);
    score_kernel<<<dim3(8, 64, 2), dim3(256), 0, stream>>>(eq, ekT, Ww, S);
    combine_kernel<<<dim3(1024), dim3(256), 0, stream>>>(S, mask, Ph, Pl, rsum);
    ctx_gemm<<<dim3(8, 64, 2), dim3(256), 0, stream>>>(Ph, Pl, vph, vpl, rsum, out);
}